// Round 2
// baseline (453.184 us; speedup 1.0000x reference)
//
#include <hip/hip_runtime.h>
#include <stdint.h>

typedef short s16x8 __attribute__((ext_vector_type(8)));
typedef short s16x4 __attribute__((ext_vector_type(4)));
typedef float f32x4 __attribute__((ext_vector_type(4)));

#define MFMA16(a, b, c) __builtin_amdgcn_mfma_f32_16x16x32_bf16(a, b, c, 0, 0, 0)

__device__ __forceinline__ short f2bf(float f) {
  uint32_t u = __builtin_bit_cast(uint32_t, f);
  u += 0x7FFFu + ((u >> 16) & 1u);   // round-to-nearest-even
  return (short)(u >> 16);
}
__device__ __forceinline__ float bf2f(short s) {
  uint32_t u = ((uint32_t)(uint16_t)s) << 16;
  return __builtin_bit_cast(float, u);
}

// ---------------------------------------------------------------------------
// Weight pre-pack (unchanged from R0): bf16, MFMA B-fragment order.
// k = ks*32 + (lane>>4)*8 + e, n = ct*16 + (lane&15).
//   W0 frags 0..15, GB 16..111, WH 112..175, D1 176..191.  192 KiB in d_ws.
// ---------------------------------------------------------------------------
__global__ void pack_w(const float* __restrict__ w0, const float* __restrict__ wh,
                       const float* __restrict__ gw, const float* __restrict__ bw,
                       const float* __restrict__ d1, short* __restrict__ out) {
  int idx = blockIdx.x * 512 + threadIdx.x;
  if (idx >= 98304) return;
  int f = idx >> 9;
  int r = idx & 511;
  int lane = r >> 3, e = r & 7;
  int kk = ((lane >> 4) << 3) + e;
  int nn = lane & 15;
  float v;
  if (f < 16) {
    int ct = f >> 1, ks = f & 1;
    int k = ks * 32 + kk, n = ct * 16 + nn;
    if (k < 48) v = w0[(1 + k) * 128 + n];
    else if (k == 48) v = w0[n];
    else v = 0.f;
  } else if (f < 112) {
    int f2 = f - 16;
    int ks = f2 & 1, ct = (f2 >> 1) & 7, gb = (f2 >> 4) & 1, l = f2 >> 5;
    int k = ks * 32 + kk, n = ct * 16 + nn;
    const float* Wp = gb ? bw : gw;
    v = Wp[(l * 64 + k) * 128 + n];
  } else if (f < 176) {
    int f2 = f - 112;
    int ks = f2 & 3, ct = (f2 >> 2) & 7, i = f2 >> 5;
    int k = ks * 32 + kk, n = ct * 16 + nn;
    v = wh[(i * 128 + k) * 128 + n];
  } else {
    int f2 = f - 176;
    int ks = f2 & 3, ct = f2 >> 2;
    int k = ks * 32 + kk, n = ct * 16 + nn;
    v = d1[k * 64 + n];
  }
  out[idx] = f2bf(v);
}

// ---------------------------------------------------------------------------
// Main fused kernel. 256 threads (4 waves), 64 rows/block, 32 KiB LDS ->
// 4 independent blocks/CU at VGPR<=128 (__launch_bounds__(256,4)).
// All LDS tiles are stored in MFMA-fragment-linear order:
//   frag(rg,ks) occupies [frag_id*1024 .. +1024), lane l's 16B at +l*16,
//   element (row,col): frag_id=(row>>4)*KS + (col>>5... ), see addr math.
// -> staging writes and ds_read_b128 fragment reads are all conflict-free,
//    no swizzle, no per-read address VALU beyond frag_id*1024 + lane*16.
// Residual x state is bf16 in LDS (RMW own elements); ts prefetched as
// 8 coalesced float4/thread at kernel entry, added in a coalesced RMW pass.
// ---------------------------------------------------------------------------
__global__ __launch_bounds__(256, 4) void ngc_main(
    const float* __restrict__ coords, const float* __restrict__ angles,
    const float* __restrict__ rho, const float* __restrict__ rho_n,
    const float* __restrict__ cf, const float* __restrict__ ts,
    const float* __restrict__ gt0, const float* __restrict__ gr0,
    const float* __restrict__ gt1, const float* __restrict__ gr1,
    const float* __restrict__ gt2, const float* __restrict__ gr2,
    const float* __restrict__ f0b, const float* __restrict__ fhb,
    const float* __restrict__ gab, const float* __restrict__ beb,
    const float* __restrict__ d1b, const float* __restrict__ d2w,
    const float* __restrict__ d2b, const short* __restrict__ pw,
    float* __restrict__ out, int n) {
  __shared__ __align__(16) char smem[32 * 1024];
  char* featA = smem;              // 8 KiB: frags (rg*2+ks), rg<4, ks<2
  char* cfA   = smem + 8 * 1024;   // 8 KiB: frags (rg*2+ks)
  char* xA    = smem + 16 * 1024;  // 16 KiB: frags (rg*4+ks), ks<4
  float* red  = (float*)smem;      // decoder partials, overlays featA (dead)

  const int tid = threadIdx.x;
  const int lane = tid & 63;
  const int w = tid >> 6;          // wave id 0..3
  const int g16 = lane >> 4;
  const int l15 = lane & 15;
  const int row0 = blockIdx.x * 64;

  // ---- ts prefetch: 8 coalesced float4 per thread, in flight from t=0 ----
  const float4* ts4 = (const float4*)ts;
  float4 tsr[8];
#pragma unroll
  for (int it = 0; it < 8; ++it) {
    int idx = it * 256 + tid;           // 64 rows x 32 float4
    int r = idx >> 5, c4 = idx & 31;
    int gr_ = row0 + r; gr_ = gr_ < n ? gr_ : n - 1;
    tsr[it] = ts4[(size_t)gr_ * 32 + c4];
  }

  // ---- bilinear gathers: 384 tasks (64 rows x 6 grids) -------------------
  {
    int r = tid & 63;
    int gr_ = row0 + r; gr_ = gr_ < n ? gr_ : n - 1;
    float c_ = coords[gr_];
    float a_ = angles[gr_];
    float rn_ = rho_n[gr_];
    auto do_g = [&](int g, float u, float v) {
      int lvl = (g < 3) ? g : g - 3;
      const float* G = (g == 0) ? gt0 : (g == 1) ? gt1 : (g == 2) ? gt2
                     : (g == 3) ? gr0 : (g == 4) ? gr1 : gr2;
      int Wg = 128 << lvl;
      float x = u * (float)(Wg - 1), y = v * (float)(Wg - 1);
      int ix = (int)x; ix = ix < 0 ? 0 : (ix > Wg - 2 ? Wg - 2 : ix);
      int iy = (int)y; iy = iy < 0 ? 0 : (iy > Wg - 2 ? Wg - 2 : iy);
      float wx = x - (float)ix, wy = y - (float)iy;
      const float4* p0 = (const float4*)(G + (size_t)(iy * Wg + ix) * 8);
      const float4* p1 = (const float4*)(G + (size_t)((iy + 1) * Wg + ix) * 8);
      float4 c00a = p0[0], c00b = p0[1], c01a = p0[2], c01b = p0[3];
      float4 c10a = p1[0], c10b = p1[1], c11a = p1[2], c11b = p1[3];
      float w00 = (1.f - wx) * (1.f - wy), w01 = wx * (1.f - wy);
      float w10 = (1.f - wx) * wy, w11 = wx * wy;
      s16x8 o;
      o[0] = f2bf(c00a.x * w00 + c01a.x * w01 + c10a.x * w10 + c11a.x * w11);
      o[1] = f2bf(c00a.y * w00 + c01a.y * w01 + c10a.y * w10 + c11a.y * w11);
      o[2] = f2bf(c00a.z * w00 + c01a.z * w01 + c10a.z * w10 + c11a.z * w11);
      o[3] = f2bf(c00a.w * w00 + c01a.w * w01 + c10a.w * w10 + c11a.w * w11);
      o[4] = f2bf(c00b.x * w00 + c01b.x * w01 + c10b.x * w10 + c11b.x * w11);
      o[5] = f2bf(c00b.y * w00 + c01b.y * w01 + c10b.y * w10 + c11b.y * w11);
      o[6] = f2bf(c00b.z * w00 + c01b.z * w01 + c10b.z * w10 + c11b.z * w11);
      o[7] = f2bf(c00b.w * w00 + c01b.w * w01 + c10b.w * w10 + c11b.w * w11);
      // feat element run (row=r, cols g*8..g*8+7) == frag(r>>4, g>>2),
      // lane slot (g&3)*16 + (r&15): a single linear 16B store.
      int dst16 = ((r >> 4) * 2 + (g >> 2)) * 64 + (g & 3) * 16 + (r & 15);
      *(s16x8*)(featA + dst16 * 16) = o;
    };
    int gA = tid >> 6;                       // grids 0..3, all waves
    do_g(gA, gA < 3 ? a_ : rn_, c_);
    if (tid < 128) {                         // grids 4..5, waves 0-1
      int gB = 4 + (tid >> 6);
      do_g(gB, rn_, c_);
    }
  }

  // ---- curve_feats -> cfA (bf16, frag-linear) ----------------------------
#pragma unroll
  for (int it = 0; it < 2; ++it) {
    int task = it * 256 + tid;               // 64 rows x 8 col-blocks
    int cb = task & 7, r = task >> 3;
    int gr_ = row0 + r; gr_ = gr_ < n ? gr_ : n - 1;
    const float4* cp = (const float4*)(cf + (size_t)gr_ * 64 + cb * 8);
    float4 v0 = cp[0], v1 = cp[1];
    s16x8 s = { f2bf(v0.x), f2bf(v0.y), f2bf(v0.z), f2bf(v0.w),
                f2bf(v1.x), f2bf(v1.y), f2bf(v1.z), f2bf(v1.w) };
    int dst16 = ((r >> 4) * 2 + (cb >> 2)) * 64 + (cb & 3) * 16 + (r & 15);
    *(s16x8*)(cfA + dst16 * 16) = s;
  }

  // ---- rho into feat col 48, zeros 49..63 --------------------------------
  if (tid < 64) {
    int r = tid;
    int gr_ = row0 + r; gr_ = gr_ < n ? gr_ : n - 1;
    s16x8 a = { f2bf(rho[gr_]), 0, 0, 0, 0, 0, 0, 0 };
    s16x8 z = { 0, 0, 0, 0, 0, 0, 0, 0 };
    int base = ((r >> 4) * 2 + 1) * 64;
    *(s16x8*)(featA + (base + 32 + (r & 15)) * 16) = a;
    *(s16x8*)(featA + (base + 48 + (r & 15)) * 16) = z;
  }
  __syncthreads();

  // frag loaders: all linear, conflict-free (lane l -> base + l*16)
  auto ldF = [&](const char* b, int frag) -> s16x8 {
    return *(const s16x8*)(b + (frag * 64 + lane) * 16);
  };
  auto ldw = [&](int frag) -> s16x8 { return ((const s16x8*)pw)[frag * 64 + lane]; };

  // ---- Layer 0: xA = bf16(silu(g0*(feat@W0+b0)+be0)) ---------------------
#pragma unroll
  for (int ct2 = 0; ct2 < 2; ++ct2) {
    int ct = w + ct2 * 4;
    int col = ct * 16 + l15;
    s16x8 bw0 = ldw(ct * 2), bw1 = ldw(ct * 2 + 1);
    s16x8 bg0 = ldw(16 + ct * 2), bg1 = ldw(16 + ct * 2 + 1);
    s16x8 bb0 = ldw(32 + ct * 2), bb1 = ldw(32 + ct * 2 + 1);
    float f0bv = f0b[col], gabv = gab[col], bebv = beb[col];
    int cbase = col >> 5, cslot = ((col >> 3) & 3) * 16, ce = (col & 7) * 2;
#pragma unroll
    for (int rg = 0; rg < 4; ++rg) {
      s16x8 a0 = ldF(featA, rg * 2), a1 = ldF(featA, rg * 2 + 1);
      s16x8 c0 = ldF(cfA, rg * 2), c1 = ldF(cfA, rg * 2 + 1);
      f32x4 t = {0.f, 0.f, 0.f, 0.f};
      t = MFMA16(a0, bw0, t); t = MFMA16(a1, bw1, t);
      f32x4 ga = {0.f, 0.f, 0.f, 0.f};
      ga = MFMA16(c0, bg0, ga); ga = MFMA16(c1, bg1, ga);
      f32x4 be = {0.f, 0.f, 0.f, 0.f};
      be = MFMA16(c0, bb0, be); be = MFMA16(c1, bb1, be);
      char* xbase = xA + (rg * 4 + cbase) * 1024 + ce;
#pragma unroll
      for (int rr = 0; rr < 4; ++rr) {
        float z = (ga[rr] + gabv) * (t[rr] + f0bv) + (be[rr] + bebv);
        float sl = z * __builtin_amdgcn_rcpf(1.f + __expf(-z));
        *(short*)(xbase + (cslot + g16 * 4 + rr) * 16) = f2bf(sl);
      }
    }
  }
  __syncthreads();

  // ---- pass B: xA += ts (coalesced RMW, consumes tsr) --------------------
#pragma unroll
  for (int it = 0; it < 8; ++it) {
    int idx = it * 256 + tid;
    int r = idx >> 5, c4 = idx & 31;
    int c = c4 * 4;
    char* p = xA + ((r >> 4) * 4 + (c >> 5)) * 1024
                 + ((((c >> 3) & 3) << 4) + (r & 15)) * 16 + (c & 7) * 2;
    s16x4 o = *(s16x4*)p;
    s16x4 nv = { f2bf(bf2f(o[0]) + tsr[it].x), f2bf(bf2f(o[1]) + tsr[it].y),
                 f2bf(bf2f(o[2]) + tsr[it].z), f2bf(bf2f(o[3]) + tsr[it].w) };
    *(s16x4*)p = nv;
  }
  __syncthreads();

  // ---- Residual FiLM blocks ----------------------------------------------
#pragma unroll
  for (int i = 0; i < 2; ++i) {
    f32x4 zs[2][4];
#pragma unroll
    for (int ct2 = 0; ct2 < 2; ++ct2) {
      int ct = w + ct2 * 4;
      int col = ct * 16 + l15;
      s16x8 bh0 = ldw(112 + i * 32 + ct * 4);
      s16x8 bh1 = ldw(112 + i * 32 + ct * 4 + 1);
      s16x8 bh2 = ldw(112 + i * 32 + ct * 4 + 2);
      s16x8 bh3 = ldw(112 + i * 32 + ct * 4 + 3);
      s16x8 bg0 = ldw(16 + (i + 1) * 32 + ct * 2);
      s16x8 bg1 = ldw(16 + (i + 1) * 32 + ct * 2 + 1);
      s16x8 bb0 = ldw(16 + (i + 1) * 32 + 16 + ct * 2);
      s16x8 bb1 = ldw(16 + (i + 1) * 32 + 16 + ct * 2 + 1);
      float fhbv = fhb[i * 128 + col];
      float gabv = gab[(i + 1) * 128 + col];
      float bebv = beb[(i + 1) * 128 + col];
#pragma unroll
      for (int rg = 0; rg < 4; ++rg) {
        s16x8 x0 = ldF(xA, rg * 4), x1 = ldF(xA, rg * 4 + 1);
        s16x8 x2 = ldF(xA, rg * 4 + 2), x3 = ldF(xA, rg * 4 + 3);
        s16x8 c0 = ldF(cfA, rg * 2), c1 = ldF(cfA, rg * 2 + 1);
        f32x4 t = {0.f, 0.f, 0.f, 0.f};
        t = MFMA16(x0, bh0, t); t = MFMA16(x1, bh1, t);
        t = MFMA16(x2, bh2, t); t = MFMA16(x3, bh3, t);
        f32x4 ga = {0.f, 0.f, 0.f, 0.f};
        ga = MFMA16(c0, bg0, ga); ga = MFMA16(c1, bg1, ga);
        f32x4 be = {0.f, 0.f, 0.f, 0.f};
        be = MFMA16(c0, bb0, be); be = MFMA16(c1, bb1, be);
        f32x4 z;
#pragma unroll
        for (int rr = 0; rr < 4; ++rr) {
          float zz = (ga[rr] + gabv) * (t[rr] + fhbv) + (be[rr] + bebv);
          z[rr] = zz * __builtin_amdgcn_rcpf(1.f + __expf(-zz));
        }
        zs[ct2][rg] = z;
      }
    }
    __syncthreads();   // all frag reads done before in-place RMW
#pragma unroll
    for (int ct2 = 0; ct2 < 2; ++ct2) {
      int ct = w + ct2 * 4;
      int col = ct * 16 + l15;
      int cbase = col >> 5, cslot = ((col >> 3) & 3) * 16, ce = (col & 7) * 2;
#pragma unroll
      for (int rg = 0; rg < 4; ++rg) {
        char* xbase = xA + (rg * 4 + cbase) * 1024 + ce;
#pragma unroll
        for (int rr = 0; rr < 4; ++rr) {
          short* p = (short*)(xbase + (cslot + g16 * 4 + rr) * 16);
          *p = f2bf(bf2f(*p) + zs[ct2][rg][rr]);
        }
      }
    }
    __syncthreads();
  }

  // ---- Decoder: relu(x@W1+b1)@W2+b2 --------------------------------------
  {
    int dcol = w * 16 + l15;
    s16x8 bd0 = ldw(176 + w * 4), bd1 = ldw(176 + w * 4 + 1);
    s16x8 bd2 = ldw(176 + w * 4 + 2), bd3 = ldw(176 + w * 4 + 3);
    float d1bv = d1b[dcol], w2v = d2w[dcol];
#pragma unroll
    for (int rg = 0; rg < 4; ++rg) {
      s16x8 x0 = ldF(xA, rg * 4), x1 = ldF(xA, rg * 4 + 1);
      s16x8 x2 = ldF(xA, rg * 4 + 2), x3 = ldF(xA, rg * 4 + 3);
      f32x4 hh = {0.f, 0.f, 0.f, 0.f};
      hh = MFMA16(x0, bd0, hh); hh = MFMA16(x1, bd1, hh);
      hh = MFMA16(x2, bd2, hh); hh = MFMA16(x3, bd3, hh);
#pragma unroll
      for (int rr = 0; rr < 4; ++rr) {
        float h = fmaxf(hh[rr] + d1bv, 0.f) * w2v;
        h += __shfl_xor(h, 1);
        h += __shfl_xor(h, 2);
        h += __shfl_xor(h, 4);
        h += __shfl_xor(h, 8);
        if (l15 == 0) red[(rg * 16 + g16 * 4 + rr) * 4 + w] = h;
      }
    }
  }
  __syncthreads();
  if (tid < 64) {
    int grow = row0 + tid;
    if (grow < n)
      out[grow] = red[tid * 4 + 0] + red[tid * 4 + 1] + red[tid * 4 + 2] +
                  red[tid * 4 + 3] + d2b[0];
  }
}

extern "C" void kernel_launch(void* const* d_in, const int* in_sizes, int n_in,
                              void* d_out, int out_size, void* d_ws, size_t ws_size,
                              hipStream_t stream) {
  int n = in_sizes[0];
  short* pw = (short*)d_ws;   // needs 192 KiB
  pack_w<<<192, 512, 0, stream>>>(
      (const float*)d_in[12],  // film0_fcW
      (const float*)d_in[14],  // filmh_fcW
      (const float*)d_in[16],  // gammaW
      (const float*)d_in[18],  // betaW
      (const float*)d_in[20],  // decW1
      pw);
  int nb = (n + 63) / 64;
  ngc_main<<<nb, 256, 0, stream>>>(
      (const float*)d_in[0],   // coords
      (const float*)d_in[1],   // angles
      (const float*)d_in[2],   // rho
      (const float*)d_in[3],   // rho_n
      (const float*)d_in[4],   // curve_feats
      (const float*)d_in[5],   // type_sample
      (const float*)d_in[6],   // gt0
      (const float*)d_in[7],   // gr0   (dict order: per level gt, gr)
      (const float*)d_in[8],   // gt1
      (const float*)d_in[9],   // gr1
      (const float*)d_in[10],  // gt2
      (const float*)d_in[11],  // gr2
      (const float*)d_in[13],  // film0_fcb
      (const float*)d_in[15],  // filmh_fcb
      (const float*)d_in[17],  // gammab
      (const float*)d_in[19],  // betab
      (const float*)d_in[21],  // decb1
      (const float*)d_in[22],  // decW2
      (const float*)d_in[23],  // decb2
      pw, (float*)d_out, n);
}

// Round 4
// 259.556 us; speedup vs baseline: 1.7460x; 1.7460x over previous
//
#include <hip/hip_runtime.h>
#include <stdint.h>

typedef short s16x8 __attribute__((ext_vector_type(8)));
typedef short s16x4 __attribute__((ext_vector_type(4)));
typedef float f32x4 __attribute__((ext_vector_type(4)));

#define MFMA16(a, b, c) __builtin_amdgcn_mfma_f32_16x16x32_bf16(a, b, c, 0, 0, 0)

__device__ __forceinline__ short f2bf(float f) {
  uint32_t u = __builtin_bit_cast(uint32_t, f);
  u += 0x7FFFu + ((u >> 16) & 1u);   // round-to-nearest-even
  return (short)(u >> 16);
}

// ---------------------------------------------------------------------------
// Weight pre-pack (unchanged): bf16, MFMA B-fragment order.
// k = ks*32 + (lane>>4)*8 + e, n = ct*16 + (lane&15).
//   W0 frags 0..15, GB 16..111, WH 112..175, D1 176..191.  192 KiB in d_ws.
// ---------------------------------------------------------------------------
__global__ void pack_w(const float* __restrict__ w0, const float* __restrict__ wh,
                       const float* __restrict__ gw, const float* __restrict__ bw,
                       const float* __restrict__ d1, short* __restrict__ out) {
  int idx = blockIdx.x * 512 + threadIdx.x;
  if (idx >= 98304) return;
  int f = idx >> 9;
  int r = idx & 511;
  int lane = r >> 3, e = r & 7;
  int kk = ((lane >> 4) << 3) + e;
  int nn = lane & 15;
  float v;
  if (f < 16) {
    int ct = f >> 1, ks = f & 1;
    int k = ks * 32 + kk, n = ct * 16 + nn;
    if (k < 48) v = w0[(1 + k) * 128 + n];
    else if (k == 48) v = w0[n];
    else v = 0.f;
  } else if (f < 112) {
    int f2 = f - 16;
    int ks = f2 & 1, ct = (f2 >> 1) & 7, gb = (f2 >> 4) & 1, l = f2 >> 5;
    int k = ks * 32 + kk, n = ct * 16 + nn;
    const float* Wp = gb ? bw : gw;
    v = Wp[(l * 64 + k) * 128 + n];
  } else if (f < 176) {
    int f2 = f - 112;
    int ks = f2 & 3, ct = (f2 >> 2) & 7, i = f2 >> 5;
    int k = ks * 32 + kk, n = ct * 16 + nn;
    v = wh[(i * 128 + k) * 128 + n];
  } else {
    int f2 = f - 176;
    int ks = f2 & 3, ct = f2 >> 2;
    int k = ks * 32 + kk, n = ct * 16 + nn;
    v = d1[k * 64 + n];
  }
  out[idx] = f2bf(v);
}

// ---------------------------------------------------------------------------
// Main fused kernel. 512 threads (8 waves), 64 rows/block, 33 KiB LDS.
// Wave w owns output col-tile ct=w (cols 16w..16w+15) for 128-wide layers;
// residual state stays f32 in registers xr[4][4].
// LDS x is a SINGLE bf16 buffer updated in place with the R0-proven
// read -> barrier -> write -> barrier pattern (two barriers per block).
// red is a DEDICATED region (no overlay).
// All LDS tiles fragment-linear: frag f at [f*1024,+1024), lane l at +l*16;
// element (row,col): frag=(row>>4)*KS+(col>>5), slot=((col>>3)&3)*16+(row&15),
// byte=(col&7)*2.  Conflict-free ds_read_b128 / writes.
// ---------------------------------------------------------------------------
__global__ __launch_bounds__(512) void ngc_main(
    const float* __restrict__ coords, const float* __restrict__ angles,
    const float* __restrict__ rho, const float* __restrict__ rho_n,
    const float* __restrict__ cf, const float* __restrict__ ts,
    const float* __restrict__ gt0, const float* __restrict__ gr0,
    const float* __restrict__ gt1, const float* __restrict__ gr1,
    const float* __restrict__ gt2, const float* __restrict__ gr2,
    const float* __restrict__ f0b, const float* __restrict__ fhb,
    const float* __restrict__ gab, const float* __restrict__ beb,
    const float* __restrict__ d1b, const float* __restrict__ d2w,
    const float* __restrict__ d2b, const short* __restrict__ pw,
    float* __restrict__ out, int n) {
  __shared__ __align__(16) char smem[33 * 1024];
  char* featA = smem;               // 8 KiB: frag = rg*2+ks (ks<2)
  char* cfA   = smem + 8 * 1024;    // 8 KiB: frag = rg*2+ks
  char* xA    = smem + 16 * 1024;   // 16 KiB: frag = rg*4+ks (ks<4)
  float* red  = (float*)(smem + 32 * 1024);  // 1 KiB, dedicated

  const int tid = threadIdx.x;
  const int lane = tid & 63;
  const int w = tid >> 6;           // wave id == col-tile ct, 0..7
  const int g16 = lane >> 4;
  const int l15 = lane & 15;
  const int row0 = blockIdx.x * 64;
  const int col = w * 16 + l15;
  const int cbase = col >> 5;
  const int cslot = ((col >> 3) & 3) * 16;
  const int ce = (col & 7) * 2;

  // ---- ts prefetch: 16 scalar f32 (wave's col, all its acc rows) ---------
  float tsr[4][4];
#pragma unroll
  for (int rg = 0; rg < 4; ++rg)
#pragma unroll
    for (int rr = 0; rr < 4; ++rr) {
      int grow = row0 + rg * 16 + g16 * 4 + rr; grow = grow < n ? grow : n - 1;
      tsr[rg][rr] = ts[(size_t)grow * 128 + col];
    }

  // ---- bilinear gathers: 384 tasks (64 rows x 6 grids), waves 0-5 --------
  if (tid < 384) {
    int r = tid & 63, g = tid >> 6;           // g wave-uniform
    int gr_ = row0 + r; gr_ = gr_ < n ? gr_ : n - 1;
    float vv = coords[gr_];
    float u = (g < 3) ? angles[gr_] : rho_n[gr_];
    int lvl = (g < 3) ? g : g - 3;
    const float* G = (g == 0) ? gt0 : (g == 1) ? gt1 : (g == 2) ? gt2
                   : (g == 3) ? gr0 : (g == 4) ? gr1 : gr2;
    int Wg = 128 << lvl;
    float x = u * (float)(Wg - 1), y = vv * (float)(Wg - 1);
    int ix = (int)x; ix = ix < 0 ? 0 : (ix > Wg - 2 ? Wg - 2 : ix);
    int iy = (int)y; iy = iy < 0 ? 0 : (iy > Wg - 2 ? Wg - 2 : iy);
    float wx = x - (float)ix, wy = y - (float)iy;
    const float4* p0 = (const float4*)(G + (size_t)(iy * Wg + ix) * 8);
    const float4* p1 = (const float4*)(G + (size_t)((iy + 1) * Wg + ix) * 8);
    float4 c00a = p0[0], c00b = p0[1], c01a = p0[2], c01b = p0[3];
    float4 c10a = p1[0], c10b = p1[1], c11a = p1[2], c11b = p1[3];
    float w00 = (1.f - wx) * (1.f - wy), w01 = wx * (1.f - wy);
    float w10 = (1.f - wx) * wy, w11 = wx * wy;
    s16x8 o;
    o[0] = f2bf(c00a.x * w00 + c01a.x * w01 + c10a.x * w10 + c11a.x * w11);
    o[1] = f2bf(c00a.y * w00 + c01a.y * w01 + c10a.y * w10 + c11a.y * w11);
    o[2] = f2bf(c00a.z * w00 + c01a.z * w01 + c10a.z * w10 + c11a.z * w11);
    o[3] = f2bf(c00a.w * w00 + c01a.w * w01 + c10a.w * w10 + c11a.w * w11);
    o[4] = f2bf(c00b.x * w00 + c01b.x * w01 + c10b.x * w10 + c11b.x * w11);
    o[5] = f2bf(c00b.y * w00 + c01b.y * w01 + c10b.y * w10 + c11b.y * w11);
    o[6] = f2bf(c00b.z * w00 + c01b.z * w01 + c10b.z * w10 + c11b.z * w11);
    o[7] = f2bf(c00b.w * w00 + c01b.w * w01 + c10b.w * w10 + c11b.w * w11);
    int dst16 = ((r >> 4) * 2 + (g >> 2)) * 64 + (g & 3) * 16 + (r & 15);
    *(s16x8*)(featA + dst16 * 16) = o;
  }

  // ---- curve_feats -> cfA (bf16, frag-linear): 512 tasks -----------------
  {
    int cb = tid & 7, r = tid >> 3;
    int gr_ = row0 + r; gr_ = gr_ < n ? gr_ : n - 1;
    const float4* cp = (const float4*)(cf + (size_t)gr_ * 64 + cb * 8);
    float4 v0 = cp[0], v1 = cp[1];
    s16x8 s = { f2bf(v0.x), f2bf(v0.y), f2bf(v0.z), f2bf(v0.w),
                f2bf(v1.x), f2bf(v1.y), f2bf(v1.z), f2bf(v1.w) };
    int dst16 = ((r >> 4) * 2 + (cb >> 2)) * 64 + (cb & 3) * 16 + (r & 15);
    *(s16x8*)(cfA + dst16 * 16) = s;
  }

  // ---- rho into feat col 48, zeros 49..63 --------------------------------
  if (tid < 64) {
    int r = tid;
    int gr_ = row0 + r; gr_ = gr_ < n ? gr_ : n - 1;
    s16x8 a = { f2bf(rho[gr_]), 0, 0, 0, 0, 0, 0, 0 };
    s16x8 z = { 0, 0, 0, 0, 0, 0, 0, 0 };
    int base = ((r >> 4) * 2 + 1) * 64;
    *(s16x8*)(featA + (base + 32 + (r & 15)) * 16) = a;
    *(s16x8*)(featA + (base + 48 + (r & 15)) * 16) = z;
  }
  __syncthreads();

  auto ldF = [&](const char* b, int frag) -> s16x8 {
    return *(const s16x8*)(b + (frag * 64 + lane) * 16);
  };
  auto ldw = [&](int frag) -> s16x8 { return ((const s16x8*)pw)[frag * 64 + lane]; };

  float xr[4][4];

  // ---- Layer 0: xr = silu(g0*(feat@W0+b0)+be0) + ts; xA = bf16(xr) -------
  {
    s16x8 bw0 = ldw(w * 2), bw1 = ldw(w * 2 + 1);
    s16x8 bg0 = ldw(16 + w * 2), bg1 = ldw(16 + w * 2 + 1);
    s16x8 bb0 = ldw(32 + w * 2), bb1 = ldw(32 + w * 2 + 1);
    float f0bv = f0b[col], gabv = gab[col], bebv = beb[col];
#pragma unroll
    for (int rg = 0; rg < 4; ++rg) {
      s16x8 a0 = ldF(featA, rg * 2), a1 = ldF(featA, rg * 2 + 1);
      s16x8 c0 = ldF(cfA, rg * 2), c1 = ldF(cfA, rg * 2 + 1);
      f32x4 t = {0.f, 0.f, 0.f, 0.f};
      t = MFMA16(a0, bw0, t); t = MFMA16(a1, bw1, t);
      f32x4 ga = {0.f, 0.f, 0.f, 0.f};
      ga = MFMA16(c0, bg0, ga); ga = MFMA16(c1, bg1, ga);
      f32x4 be = {0.f, 0.f, 0.f, 0.f};
      be = MFMA16(c0, bb0, be); be = MFMA16(c1, bb1, be);
      char* xbase = xA + (rg * 4 + cbase) * 1024 + ce;
#pragma unroll
      for (int rr = 0; rr < 4; ++rr) {
        float z = (ga[rr] + gabv) * (t[rr] + f0bv) + (be[rr] + bebv);
        float sl = z * __builtin_amdgcn_rcpf(1.f + __expf(-z));
        xr[rg][rr] = sl + tsr[rg][rr];
        *(short*)(xbase + (cslot + g16 * 4 + rr) * 16) = f2bf(xr[rg][rr]);
      }
    }
  }
  __syncthreads();

  // ---- Residual FiLM blocks: read xA -> barrier -> write xA -> barrier ---
#pragma unroll
  for (int i = 0; i < 2; ++i) {
    s16x8 bh0 = ldw(112 + i * 32 + w * 4);
    s16x8 bh1 = ldw(112 + i * 32 + w * 4 + 1);
    s16x8 bh2 = ldw(112 + i * 32 + w * 4 + 2);
    s16x8 bh3 = ldw(112 + i * 32 + w * 4 + 3);
    s16x8 bg0 = ldw(16 + (i + 1) * 32 + w * 2);
    s16x8 bg1 = ldw(16 + (i + 1) * 32 + w * 2 + 1);
    s16x8 bb0 = ldw(16 + (i + 1) * 32 + 16 + w * 2);
    s16x8 bb1 = ldw(16 + (i + 1) * 32 + 16 + w * 2 + 1);
    float fhbv = fhb[i * 128 + col];
    float gabv = gab[(i + 1) * 128 + col];
    float bebv = beb[(i + 1) * 128 + col];
    f32x4 zs[4];
#pragma unroll
    for (int rg = 0; rg < 4; ++rg) {
      s16x8 xa = ldF(xA, rg * 4), xb = ldF(xA, rg * 4 + 1);
      s16x8 xc = ldF(xA, rg * 4 + 2), xd = ldF(xA, rg * 4 + 3);
      s16x8 c0 = ldF(cfA, rg * 2), c1 = ldF(cfA, rg * 2 + 1);
      f32x4 t = {0.f, 0.f, 0.f, 0.f};
      t = MFMA16(xa, bh0, t); t = MFMA16(xb, bh1, t);
      t = MFMA16(xc, bh2, t); t = MFMA16(xd, bh3, t);
      f32x4 ga = {0.f, 0.f, 0.f, 0.f};
      ga = MFMA16(c0, bg0, ga); ga = MFMA16(c1, bg1, ga);
      f32x4 be = {0.f, 0.f, 0.f, 0.f};
      be = MFMA16(c0, bb0, be); be = MFMA16(c1, bb1, be);
      f32x4 z;
#pragma unroll
      for (int rr = 0; rr < 4; ++rr) {
        float zz = (ga[rr] + gabv) * (t[rr] + fhbv) + (be[rr] + bebv);
        z[rr] = zz * __builtin_amdgcn_rcpf(1.f + __expf(-zz));
      }
      zs[rg] = z;
    }
    __syncthreads();   // all waves' MFMA reads of xA complete
#pragma unroll
    for (int rg = 0; rg < 4; ++rg) {
      char* xbase = xA + (rg * 4 + cbase) * 1024 + ce;
#pragma unroll
      for (int rr = 0; rr < 4; ++rr) {
        xr[rg][rr] += zs[rg][rr];
        *(short*)(xbase + (cslot + g16 * 4 + rr) * 16) = f2bf(xr[rg][rr]);
      }
    }
    __syncthreads();   // in-place writes complete
  }

  // ---- Decoder: relu(x@W1+b1)@W2+b2 (reads xA, writes dedicated red) -----
  {
    int ctd = w & 3, rbase = (w >> 2) * 2;
    int dcol = ctd * 16 + l15;
    s16x8 bd0 = ldw(176 + ctd * 4), bd1 = ldw(176 + ctd * 4 + 1);
    s16x8 bd2 = ldw(176 + ctd * 4 + 2), bd3 = ldw(176 + ctd * 4 + 3);
    float d1bv = d1b[dcol], w2v = d2w[dcol];
#pragma unroll
    for (int q = 0; q < 2; ++q) {
      int rg = rbase + q;
      s16x8 xa = ldF(xA, rg * 4), xb = ldF(xA, rg * 4 + 1);
      s16x8 xc = ldF(xA, rg * 4 + 2), xd = ldF(xA, rg * 4 + 3);
      f32x4 hh = {0.f, 0.f, 0.f, 0.f};
      hh = MFMA16(xa, bd0, hh); hh = MFMA16(xb, bd1, hh);
      hh = MFMA16(xc, bd2, hh); hh = MFMA16(xd, bd3, hh);
#pragma unroll
      for (int rr = 0; rr < 4; ++rr) {
        float h = fmaxf(hh[rr] + d1bv, 0.f) * w2v;
        h += __shfl_xor(h, 1);
        h += __shfl_xor(h, 2);
        h += __shfl_xor(h, 4);
        h += __shfl_xor(h, 8);
        if (l15 == 0) red[(rg * 16 + g16 * 4 + rr) * 4 + ctd] = h;
      }
    }
  }
  __syncthreads();
  if (tid < 64) {
    int grow = row0 + tid;
    if (grow < n)
      out[grow] = red[tid * 4 + 0] + red[tid * 4 + 1] + red[tid * 4 + 2] +
                  red[tid * 4 + 3] + d2b[0];
  }
}

extern "C" void kernel_launch(void* const* d_in, const int* in_sizes, int n_in,
                              void* d_out, int out_size, void* d_ws, size_t ws_size,
                              hipStream_t stream) {
  int n = in_sizes[0];
  short* pw = (short*)d_ws;   // needs 192 KiB
  pack_w<<<192, 512, 0, stream>>>(
      (const float*)d_in[12],  // film0_fcW
      (const float*)d_in[14],  // filmh_fcW
      (const float*)d_in[16],  // gammaW
      (const float*)d_in[18],  // betaW
      (const float*)d_in[20],  // decW1
      pw);
  int nb = (n + 63) / 64;
  ngc_main<<<nb, 512, 0, stream>>>(
      (const float*)d_in[0],   // coords
      (const float*)d_in[1],   // angles
      (const float*)d_in[2],   // rho
      (const float*)d_in[3],   // rho_n
      (const float*)d_in[4],   // curve_feats
      (const float*)d_in[5],   // type_sample
      (const float*)d_in[6],   // gt0
      (const float*)d_in[7],   // gr0   (dict order: per level gt, gr)
      (const float*)d_in[8],   // gt1
      (const float*)d_in[9],   // gr1
      (const float*)d_in[10],  // gt2
      (const float*)d_in[11],  // gr2
      (const float*)d_in[13],  // film0_fcb
      (const float*)d_in[15],  // filmh_fcb
      (const float*)d_in[17],  // gammab
      (const float*)d_in[19],  // betab
      (const float*)d_in[21],  // decb1
      (const float*)d_in[22],  // decW2
      (const float*)d_in[23],  // decb2
      pw, (float*)d_out, n);
}